// Round 12
// baseline (1028.372 us; speedup 1.0000x reference)
//
#include <hip/hip_runtime.h>
#include <math.h>

// Problem constants
#define B_DIM 8
#define T_DIM 4096
#define K_DIM 1024   // IN_DIM
#define H_DIM 1024   // HIDDEN
#define M_DIM (B_DIM * T_DIM)   // 32768 rows
#define BK 64
#define NKT 16              // K-tiles per block (K/BK)
#define NSEG 16             // T segments of 256 rows
#define NCHAIN 512          // 8 batches x 64 col-tiles

typedef short bf16x8 __attribute__((ext_vector_type(8)));   // 8 bf16 = 4 VGPRs
typedef float f32x4  __attribute__((ext_vector_type(4)));

// ---------- helpers ----------
__device__ __forceinline__ unsigned short f2bf(float f) {
  unsigned int u = __builtin_bit_cast(unsigned int, f);
  u += 0x7FFFu + ((u >> 16) & 1u);   // round-to-nearest-even
  return (unsigned short)(u >> 16);
}

__device__ __forceinline__ void gload_lds16(const void* g, void* l) {
  __builtin_amdgcn_global_load_lds(
      (const __attribute__((address_space(1))) unsigned int*)g,
      (__attribute__((address_space(3))) unsigned int*)l,
      16 /*bytes, literal*/, 0 /*offset*/, 0 /*aux*/);
}

__device__ __forceinline__ float softplus_fast(float x) {
  float e = __expf(-fabsf(x));
  return fmaxf(x, 0.f) + __logf(1.f + e);
}

// fast tanh: 1 - 2/(e^{2x}+1). e=inf -> 1, e=0 -> -1 (correct saturation).
__device__ __forceinline__ float tanh_fast(float x) {
  float e = __expf(2.f * x);
  return 1.f - 2.f * __builtin_amdgcn_rcpf(e + 1.f);
}

// ---------- f32 -> bf16 convert (8 elems/thread) ----------
__global__ __launch_bounds__(256) void k_cvt(const float* __restrict__ in,
                                             unsigned short* __restrict__ out,
                                             int n8) {
  int i = blockIdx.x * 256 + threadIdx.x;
  if (i >= n8) return;
  float4 v0 = ((const float4*)in)[i * 2 + 0];
  float4 v1 = ((const float4*)in)[i * 2 + 1];
  bf16x8 r;
  r[0] = (short)f2bf(v0.x); r[1] = (short)f2bf(v0.y);
  r[2] = (short)f2bf(v0.z); r[3] = (short)f2bf(v0.w);
  r[4] = (short)f2bf(v1.x); r[5] = (short)f2bf(v1.y);
  r[6] = (short)f2bf(v1.z); r[7] = (short)f2bf(v1.w);
  ((bf16x8*)out)[i] = r;
}

// ---------- flag clear (re-run every launch -> replay-deterministic) ------
__global__ __launch_bounds__(256) void k_clear(unsigned int* __restrict__ f) {
  f[blockIdx.x * 256 + threadIdx.x] = 0u;
}

// ---------- mega-lookback: dual GEMM + cross-segment h-chain + tanh -------
// Grid = 8192 blocks x 256 thr (4 waves): wgid = seg*512 + col*8 + batch.
// Block = (batch, 16-col tile, 256-row T-segment). GEMM inner loop, swizzle
// and scan arithmetic are bit-identical to R9's k_mega (one m-tile's worth).
// The h-state crosses segments by decoupled lookback: after its (poll-free)
// epilogue math, a block polls flag[chain][seg-1], composes, PUBLISHES
// h_end (release: data write -> threadfence -> atomicExch flag), then
// applies + writes out. Predecessor (wgid-512) is dispatched earlier and
// runs on the SAME XCD (wgid&7 preserved) -> same-L2 chain, short polls.
// L2 locality: the ~512 resident blocks are one seg-round; the 64 col-blocks
// of a (b,seg) read the same 512KB A-panel within a tight window.
__global__ __launch_bounds__(256, 2) void k_mega(
    const unsigned short* __restrict__ Xb,    // [M][K] bf16 bits
    const unsigned short* __restrict__ Wdb,   // [H][K] bf16 bits
    const unsigned short* __restrict__ Wbb,   // [H][K] bf16 bits
    const float* __restrict__ bd,
    const float* __restrict__ bb,
    const float* __restrict__ A_log,
    const float* __restrict__ h0,             // [B][H]
    float* __restrict__ chainh,               // [NCHAIN*NSEG][16]
    unsigned int* __restrict__ flags,         // [NCHAIN*NSEG]
    float* __restrict__ out)                  // [B][T][H]
{
  __shared__ unsigned short As[2][256 * BK];   // 64 KiB
  __shared__ unsigned short Bs[2][32 * BK];    //  8 KiB
  __shared__ float totA[4][16], totB[4][16];   // chunk affine totals
  __shared__ float hs_sh[16];                  // segment-start h

  const int tid   = threadIdx.x;
  const int wgid  = blockIdx.x;
  const int batch = wgid & 7;          // == XCD (preserved across segs)
  const int col   = (wgid >> 3) & 63;  // 16-col tile
  const int seg   = wgid >> 9;         // T segment (0..15)
  const int bn    = col * 16;
  const int fcid  = (batch * 64 + col) * NSEG;   // flag/chain base

  const int w    = tid >> 6;       // wave = chunk row-group c (0..3)
  const int lane = tid & 63;
  const int c    = w;
  const int fr   = lane & 15;      // column within 16
  const int hi   = lane >> 4;      // row quad
  const int gcol = bn + fr;

  // per-thread column scalars
  const float bdv = bd[gcol];
  const float bbv = bb[gcol];
  const float Ah  = __expf(A_log[gcol]);

  // ---- staging invariants: pre-swizzled global sources (cg = ch^(row&7)) -
  const unsigned short* gA[8];
  int ldsA[8];
#pragma unroll
  for (int jj = 0; jj < 8; jj++) {
    int idx = jj * 256 + tid;      // 0..2047, row 0..255
    int row = idx >> 3;
    int cg  = (idx & 7) ^ (row & 7);
    ldsA[jj] = idx * 16;
    gA[jj] = Xb + (((size_t)(batch * T_DIM + seg * 256 + row)) << 10)
                + (size_t)(cg * 8);
  }
  const unsigned short* gB;
  int ldsB;
  {
    int idx = tid;                 // 256 chunks, vrow 0..31
    int vr  = idx >> 3;
    int cg  = (idx & 7) ^ (vr & 7);
    ldsB = idx * 16;
    int h = bn + (vr & 15);
    const unsigned short* Wsrc = (vr & 16) ? Wbb : Wdb;
    gB = Wsrc + (((size_t)h) << 10) + (size_t)(cg * 8);
  }

  // ---- ds_read bases: swizzled chunk hi^(fr&7) is fragment-independent ---
  const int ch0 = hi ^ (fr & 7);
  const char* bA0 = (const char*)As + ((c * 64 + fr) * 128 + ch0 * 16);
  const char* bA1 = (const char*)As + ((c * 64 + fr) * 128 + (ch0 ^ 4) * 16);
  const char* bB0 = (const char*)Bs + (fr * 128 + ch0 * 16);
  const char* bB1 = (const char*)Bs + (fr * 128 + (ch0 ^ 4) * 16);

// k-tile TT = 0..15; elem offset = TT*64
#define STAGE(TT, D)                                                          \
  do {                                                                        \
    int kOff = (TT) << 6;                                                     \
    _Pragma("unroll")                                                         \
    for (int jj = 0; jj < 8; jj++)                                            \
      gload_lds16(gA[jj] + kOff, (char*)As[D] + ldsA[jj]);                    \
    gload_lds16(gB + kOff, (char*)Bs[D] + ldsB);                              \
  } while (0)

#define TILE(TT, D)                                                           \
  do {                                                                        \
    if ((TT) < NKT - 1) STAGE((TT) + 1, (D) ^ 1);                             \
    bf16x8 Af[8], Bf[4];                                                      \
    _Pragma("unroll")                                                         \
    for (int mm = 0; mm < 4; mm++) {                                          \
      Af[mm * 2 + 0] = *(const bf16x8*)(bA0 + (D) * 32768 + mm * 2048);       \
      Af[mm * 2 + 1] = *(const bf16x8*)(bA1 + (D) * 32768 + mm * 2048);       \
    }                                                                         \
    _Pragma("unroll")                                                         \
    for (int nn = 0; nn < 2; nn++) {                                          \
      Bf[nn * 2 + 0] = *(const bf16x8*)(bB0 + (D) * 4096 + nn * 2048);        \
      Bf[nn * 2 + 1] = *(const bf16x8*)(bB1 + (D) * 4096 + nn * 2048);        \
    }                                                                         \
    __builtin_amdgcn_s_setprio(1);                                            \
    _Pragma("unroll")                                                         \
    for (int mm = 0; mm < 4; mm++)                                            \
      _Pragma("unroll")                                                       \
      for (int nn = 0; nn < 2; nn++)                                          \
        _Pragma("unroll")                                                     \
        for (int kk = 0; kk < 2; kk++)                                        \
          acc[mm][nn] = __builtin_amdgcn_mfma_f32_16x16x32_bf16(              \
              Af[mm * 2 + kk], Bf[nn * 2 + kk], acc[mm][nn], 0, 0, 0);        \
    __builtin_amdgcn_s_setprio(0);                                            \
    asm volatile("s_waitcnt vmcnt(0)" ::: "memory");                          \
    __builtin_amdgcn_s_barrier();                                             \
  } while (0)

  // prologue
  STAGE(0, 0);
  asm volatile("s_waitcnt vmcnt(0)" ::: "memory");
  __builtin_amdgcn_s_barrier();

  const f32x4 z4 = {0.f, 0.f, 0.f, 0.f};
  f32x4 acc[4][2];
#pragma unroll
  for (int m = 0; m < 4; m++) { acc[m][0] = z4; acc[m][1] = z4; }

#pragma unroll 1
  for (int kp = 0; kp < 8; kp++) {
    TILE(kp * 2, 0);
    TILE(kp * 2 + 1, 1);
  }

  // ---- epilogue: nonlinearity + within-chunk prefix (poll-free part) ----
  // C/D layout: col = lane&15, row-in-frag = hi*4 + r  [m89-verified].
  float rA[4], rB[4], wAp[4][4], wBp[4][4];
#pragma unroll
  for (int m = 0; m < 4; m++) {
    float A_ = 1.f, B_ = 0.f;
#pragma unroll
    for (int r = 0; r < 4; r++) {
      float z1  = acc[m][0][r] + bdv;
      float z2  = acc[m][1][r] + bbv;
      float dlt = softplus_fast(z1);
      float av  = __expf(-dlt * Ah);
      float bv  = dlt * z2;
      B_ = fmaf(av, B_, bv);          // compose (A_,B_) then (av,bv)
      A_ *= av;
      wAp[m][r] = A_; wBp[m][r] = B_; // inclusive within-run prefix
    }
    rA[m] = A_; rB[m] = B_;           // run total
  }
  // exclusive prefix over the 16 runs (t-order rho = m*4 + hi), snapshotted
  float cA = 1.f, cB = 0.f, eA[4], eB[4];
#pragma unroll
  for (int rho = 0; rho < 16; rho++) {
    if ((rho & 3) == hi) { eA[rho >> 2] = cA; eB[rho >> 2] = cB; }
    float sa = __shfl(rA[rho >> 2], (rho & 3) * 16 + fr, 64);
    float sb = __shfl(rB[rho >> 2], (rho & 3) * 16 + fr, 64);
    cB = fmaf(sa, cB, sb);
    cA *= sa;
  }
  // (cA,cB) = full chunk total
  if (hi == 0) { totA[c][fr] = cA; totB[c][fr] = cB; }
  __syncthreads();

  // ---- lookback: resolve segment-start h ----
  if (seg != 0 && tid == 0) {
    while (atomicOr(&flags[fcid + seg - 1], 0u) == 0u)
      __builtin_amdgcn_s_sleep(2);
  }
  __syncthreads();
  __threadfence();                    // acquire: invalidate L1, order reads
  if (tid < 16)
    hs_sh[tid] = (seg == 0) ? h0[(batch << 10) + bn + tid]
                            : chainh[(size_t)(fcid + seg - 1) * 16 + tid];
  __syncthreads();

  float hs = hs_sh[fr];               // h at segment start
#pragma unroll
  for (int cc = 0; cc < 3; cc++) {    // compose chunks before mine
    float t2 = fmaf(totA[cc][fr], hs, totB[cc][fr]);
    hs = (cc < c) ? t2 : hs;
  }

  // ---- publish h_end (before apply -> minimal chain latency) ----
  if (c == 3) {
    float hend = fmaf(cA, hs, cB);
    if (lane < 16) chainh[(size_t)(fcid + seg) * 16 + fr] = hend;
    __threadfence();                  // release: data before flag
    if (lane == 0) atomicExch(&flags[fcid + seg], 1u);
  }

  // ---- apply: h_t = (excl ∘ within-run)(hs); write tanh(h_t) ----
  size_t obase =
      (((size_t)(batch * T_DIM + seg * 256 + c * 64 + hi * 4)) << 10)
      + (size_t)gcol;
#pragma unroll
  for (int m = 0; m < 4; m++) {
#pragma unroll
    for (int r = 0; r < 4; r++) {
      float aT = eA[m] * wAp[m][r];
      float bT = fmaf(wAp[m][r], eB[m], wBp[m][r]);
      float h  = fmaf(aT, hs, bT);
      out[obase + ((size_t)(m * 16 + r) << 10)] = tanh_fast(h);
    }
  }
#undef TILE
#undef STAGE
}

// ---------- launch ----------
extern "C" void kernel_launch(void* const* d_in, const int* in_sizes, int n_in,
                              void* d_out, int out_size, void* d_ws, size_t ws_size,
                              hipStream_t stream) {
  const float* x     = (const float*)d_in[0];
  const float* h0    = (const float*)d_in[1];
  const float* Wd    = (const float*)d_in[2];
  const float* bd    = (const float*)d_in[3];
  const float* Wb    = (const float*)d_in[4];
  const float* bb    = (const float*)d_in[5];
  const float* A_log = (const float*)d_in[6];
  float* out = (float*)d_out;

  char* ws = (char*)d_ws;
  unsigned short* xb     = (unsigned short*)(ws + 0);           // 64 MiB
  unsigned short* wdb    = (unsigned short*)(ws + 67108864);    //  2 MiB
  unsigned short* wbb    = (unsigned short*)(ws + 69206016);    //  2 MiB
  float*          chainh = (float*)(ws + 71303168);             // 512 KiB
  unsigned int*   flags  = (unsigned int*)(ws + 71827456);      //  32 KiB

  // converts + flag clear (re-runs every replay -> deterministic)
  k_cvt<<<(M_DIM * K_DIM / 8) / 256, 256, 0, stream>>>(x, xb, M_DIM * K_DIM / 8);
  k_cvt<<<(H_DIM * K_DIM / 8) / 256, 256, 0, stream>>>(Wd, wdb, H_DIM * K_DIM / 8);
  k_cvt<<<(H_DIM * K_DIM / 8) / 256, 256, 0, stream>>>(Wb, wbb, H_DIM * K_DIM / 8);
  k_clear<<<(NCHAIN * NSEG) / 256, 256, 0, stream>>>(flags);

  // fused dual GEMM + decoupled-lookback scan + tanh
  k_mega<<<NCHAIN * NSEG, 256, 0, stream>>>(xb, wdb, wbb, bd, bb, A_log, h0,
                                            chainh, flags, out);
}

// Round 13
// 385.070 us; speedup vs baseline: 2.6706x; 2.6706x over previous
//
#include <hip/hip_runtime.h>
#include <math.h>

// Problem constants
#define B_DIM 8
#define T_DIM 4096
#define K_DIM 1024   // IN_DIM
#define H_DIM 1024   // HIDDEN
#define M_DIM (B_DIM * T_DIM)   // 32768 rows

typedef short bf16x8 __attribute__((ext_vector_type(8)));   // 8 bf16 = 4 VGPRs
typedef float f32x4  __attribute__((ext_vector_type(4)));

// ---------- helpers ----------
__device__ __forceinline__ unsigned short f2bf(float f) {
  unsigned int u = __builtin_bit_cast(unsigned int, f);
  u += 0x7FFFu + ((u >> 16) & 1u);   // round-to-nearest-even
  return (unsigned short)(u >> 16);
}

__device__ __forceinline__ void gload_lds16(const void* g, void* l) {
  __builtin_amdgcn_global_load_lds(
      (const __attribute__((address_space(1))) unsigned int*)g,
      (__attribute__((address_space(3))) unsigned int*)l, 16, 0, 0);
}
__device__ __forceinline__ void gload_lds4(const void* g, void* l) {
  __builtin_amdgcn_global_load_lds(
      (const __attribute__((address_space(1))) unsigned int*)g,
      (__attribute__((address_space(3))) unsigned int*)l, 4, 0, 0);
}

__device__ __forceinline__ float softplus_fast(float x) {
  float e = __expf(-fabsf(x));
  return fmaxf(x, 0.f) + __logf(1.f + e);
}

// fast tanh: 1 - 2/(e^{2x}+1). e=inf -> 1, e=0 -> -1 (correct saturation).
__device__ __forceinline__ float tanh_fast(float x) {
  float e = __expf(2.f * x);
  return 1.f - 2.f * __builtin_amdgcn_rcpf(e + 1.f);
}

#define LGKM_BAR()                                                            \
  do {                                                                        \
    asm volatile("s_waitcnt lgkmcnt(0)" ::: "memory");                        \
    __builtin_amdgcn_sched_barrier(0);                                        \
    __builtin_amdgcn_s_barrier();                                             \
  } while (0)

// ---------- f32 -> bf16 convert (8 elems/thread) ----------
__global__ __launch_bounds__(256) void k_cvt(const float* __restrict__ in,
                                             unsigned short* __restrict__ out,
                                             int n8) {
  int i = blockIdx.x * 256 + threadIdx.x;
  if (i >= n8) return;
  float4 v0 = ((const float4*)in)[i * 2 + 0];
  float4 v1 = ((const float4*)in)[i * 2 + 1];
  bf16x8 r;
  r[0] = (short)f2bf(v0.x); r[1] = (short)f2bf(v0.y);
  r[2] = (short)f2bf(v0.z); r[3] = (short)f2bf(v0.w);
  r[4] = (short)f2bf(v1.x); r[5] = (short)f2bf(v1.y);
  r[6] = (short)f2bf(v1.z); r[7] = (short)f2bf(v1.w);
  ((bf16x8*)out)[i] = r;
}

// ---------- megakernel v4: counted-vmcnt depth-3 pipeline ------------------
// R9 geometry/epilogue verbatim: 512 blocks (batch,16-col) x 256 thr (4 waves
// = 4 scan chunks), 2 blocks/CU. NEW: flat loop over 512 half-tiles (BK=32),
// 4 A-buffers (16 KB each) + 4 B-buffers (2 KB each) = 72 KB.
// PAIRED-ROW layout keeps the verified conflict-free 128B XOR swizzle at
// BK=32: LDS row r holds real rows r and r+128 (A) / v and v+16 (B); chunk
// c_g = slot ^ (r&7); real = r + 128*(c_g>>2); k-chunk = c_g&3. Read slot =
// ((R>>7)*4 + hi) ^ (fr&7) is wave-constant in R>>7 -> zero-VALU addressing.
// Schedule per half H: s_waitcnt vmcnt(12) [drains ONLY H's 6 loads; H+1,H+2
// stay in flight], s_barrier, STAGE(H+3), ds_read+8 MFMA. Loads age 3 halves.
// Per-m-tile epilogue (every 32 halves) = R9 scan math; ends with vmcnt(0)
// (stores + flights drained -> counting stays exact; data already in LDS).
__global__ __launch_bounds__(256, 2) void k_mega(
    const unsigned short* __restrict__ Xb,    // [M][K] bf16 bits
    const unsigned short* __restrict__ Wdb,   // [H][K] bf16 bits
    const unsigned short* __restrict__ Wbb,   // [H][K] bf16 bits
    const float* __restrict__ bd,
    const float* __restrict__ bb,
    const float* __restrict__ A_log,
    const float* __restrict__ h0,             // [B][H]
    float* __restrict__ out)                  // [B][T][H]
{
  __shared__ unsigned short Ab[4][8192];       // 4 x 16 KiB (128 rows x 128B)
  __shared__ unsigned short Bb[4][1024];       // 4 x  2 KiB ( 16 rows x 128B)
  __shared__ float totA[4][16], totB[4][16];
  __shared__ float h_state[16];

  const int tid   = threadIdx.x;
  const int wg    = blockIdx.x;
  const int batch = wg & 7;        // == XCD (round-robin dispatch)
  const int bn    = (wg >> 3) * 16;

  const int c    = tid >> 6;       // wave = chunk row-group (0..3)
  const int lane = tid & 63;
  const int fr   = lane & 15;
  const int hi   = lane >> 4;      // k-chunk within BK=32 (k = hi*8)
  const int gcol = bn + fr;

  const float bdv = bd[gcol];
  const float bbv = bb[gcol];
  const float Ah  = __expf(A_log[gcol]);

  // ---- A staging invariants: 4 x 16B chunks/thread/half ----
  const unsigned short* gA[4];
  int ldsA[4];
#pragma unroll
  for (int jj = 0; jj < 4; jj++) {
    int idx = jj * 256 + tid;      // 0..1023 chunk id
    int r   = idx >> 3;            // LDS row 0..127
    int cs  = idx & 7;             // slot
    int cg  = cs ^ (r & 7);        // global chunk
    int Rg  = r + 128 * (cg >> 2); // real row 0..255 within m-tile
    int qg  = cg & 3;              // k-chunk
    ldsA[jj] = idx * 16;
    gA[jj] = Xb + (((size_t)(batch * T_DIM + Rg)) << 10) + (size_t)(qg * 8);
  }
  // ---- B staging invariants: 2 x 4B words/thread/half ----
  const unsigned short* gB[2];
  int ldsB[2];
#pragma unroll
  for (int j = 0; j < 2; j++) {
    int widx = j * 256 + tid;      // 0..511 word id (2 KB)
    int rv   = widx >> 5;          // LDS row 0..15
    int ww   = widx & 31;          // word in row
    int cs   = ww >> 2;            // slot chunk
    int wq   = ww & 3;             // word in chunk
    int cg   = cs ^ (rv & 7);
    int dual = cg >> 2;            // 0 = Wd, 1 = Wb
    int kc   = cg & 3;
    ldsB[j] = widx * 4;
    const unsigned short* Wsrc = dual ? Wbb : Wdb;
    gB[j] = Wsrc + (((size_t)(bn + rv)) << 10) + (size_t)(kc * 8 + wq * 2);
  }

  // ---- ds_read bases (zero-VALU; all loop offsets are immediates) ----
  const int slA = ((c >> 1) * 4 + hi) ^ (fr & 7);
  const char* bA  = (const char*)Ab + (((c & 1) * 64 + fr) * 128 + slA * 16);
  const char* bB0 = (const char*)Bb + (fr * 128 + ((hi)     ^ (fr & 7)) * 16);
  const char* bB1 = (const char*)Bb + (fr * 128 + ((4 + hi) ^ (fr & 7)) * 16);

// stage half HH into buffer BUF (= HH&3, compile-time at call sites)
#define STAGE(HH, BUF)                                                        \
  do {                                                                        \
    int aoff = (((HH) >> 5) << 18) + (((HH) & 31) << 5);                      \
    int boff = ((HH) & 31) << 5;                                              \
    _Pragma("unroll")                                                         \
    for (int jj = 0; jj < 4; jj++)                                            \
      gload_lds16(gA[jj] + aoff, (char*)Ab + ((BUF) << 14) + ldsA[jj]);       \
    _Pragma("unroll")                                                         \
    for (int j = 0; j < 2; j++)                                               \
      gload_lds4(gB[j] + boff, (char*)Bb + ((BUF) << 11) + ldsB[j]);          \
  } while (0)

// one half-tile: J = H&3 (compile-time), VMC = literal wait count
#define HALF(H, J, VMC, DOSTAGE)                                              \
  do {                                                                        \
    asm volatile("s_waitcnt vmcnt(" #VMC ")" ::: "memory");                   \
    __builtin_amdgcn_s_barrier();                                             \
    if (DOSTAGE) STAGE((H) + 3, ((J) + 3) & 3);                               \
    bf16x8 Af[4], Bf[2];                                                      \
    _Pragma("unroll")                                                         \
    for (int mm = 0; mm < 4; mm++)                                            \
      Af[mm] = *(const bf16x8*)(bA + (J) * 16384 + mm * 2048);                \
    Bf[0] = *(const bf16x8*)(bB0 + (J) * 2048);                               \
    Bf[1] = *(const bf16x8*)(bB1 + (J) * 2048);                               \
    __builtin_amdgcn_s_setprio(1);                                            \
    _Pragma("unroll")                                                         \
    for (int mm = 0; mm < 4; mm++)                                            \
      _Pragma("unroll")                                                       \
      for (int nn = 0; nn < 2; nn++)                                          \
        acc[mm][nn] = __builtin_amdgcn_mfma_f32_16x16x32_bf16(                \
            Af[mm], Bf[nn], acc[mm][nn], 0, 0, 0);                            \
    __builtin_amdgcn_s_setprio(0);                                            \
  } while (0)

  const f32x4 z4 = {0.f, 0.f, 0.f, 0.f};
  f32x4 acc[4][2];
#pragma unroll
  for (int m = 0; m < 4; m++) { acc[m][0] = z4; acc[m][1] = z4; }

  // ---- epilogue: R9's verified scan math (LGKM barriers, vmcnt(0) at end) -
  auto epilogue = [&](int mt) {
    float rA[4], rB[4], wAp[4][4], wBp[4][4];
#pragma unroll
    for (int m = 0; m < 4; m++) {
      float A_ = 1.f, B_ = 0.f;
#pragma unroll
      for (int r = 0; r < 4; r++) {
        float z1  = acc[m][0][r] + bdv;
        float z2  = acc[m][1][r] + bbv;
        float dlt = softplus_fast(z1);
        float av  = __expf(-dlt * Ah);
        float bv  = dlt * z2;
        B_ = fmaf(av, B_, bv);
        A_ *= av;
        wAp[m][r] = A_; wBp[m][r] = B_;
      }
      rA[m] = A_; rB[m] = B_;
    }
    float cA = 1.f, cB = 0.f, eA[4], eB[4];
#pragma unroll
    for (int rho = 0; rho < 16; rho++) {
      if ((rho & 3) == hi) { eA[rho >> 2] = cA; eB[rho >> 2] = cB; }
      float sa = __shfl(rA[rho >> 2], (rho & 3) * 16 + fr, 64);
      float sb = __shfl(rB[rho >> 2], (rho & 3) * 16 + fr, 64);
      cB = fmaf(sa, cB, sb);
      cA *= sa;
    }
    if (hi == 0) { totA[c][fr] = cA; totB[c][fr] = cB; }
    LGKM_BAR();
    float hs = h_state[fr];
#pragma unroll
    for (int cc = 0; cc < 3; cc++) {
      float t2 = fmaf(totA[cc][fr], hs, totB[cc][fr]);
      hs = (cc < c) ? t2 : hs;
    }
    LGKM_BAR();
    if (c == 3 && hi == 0) h_state[fr] = fmaf(cA, hs, cB);

    size_t obase =
        (((size_t)(batch * T_DIM + mt * 256 + c * 64 + hi * 4)) << 10)
        + (size_t)gcol;
#pragma unroll
    for (int m = 0; m < 4; m++)
#pragma unroll
      for (int r = 0; r < 4; r++) {
        float aT = eA[m] * wAp[m][r];
        float bT = fmaf(wAp[m][r], eB[m], wBp[m][r]);
        float h  = fmaf(aT, hs, bT);
        out[obase + ((size_t)(m * 16 + r) << 10)] = tanh_fast(h);
      }
    // drain stores + in-flight stages (data already in LDS) -> exact counts
    asm volatile("s_waitcnt vmcnt(0)" ::: "memory");
#pragma unroll
    for (int m = 0; m < 4; m++) { acc[m][0] = z4; acc[m][1] = z4; }
  };

  // ---- prologue: h0 init first (its wait drains nothing else), 3 stages --
  if (tid < 16) h_state[tid] = h0[(batch << 10) + bn + tid];
  STAGE(0, 0); STAGE(1, 1); STAGE(2, 2);

  // ---- flat 512-half pipeline ----
#pragma unroll 1
  for (int hb = 0; hb < 508; hb += 4) {
    HALF(hb + 0, 0, 12, true);
    HALF(hb + 1, 1, 12, true);
    HALF(hb + 2, 2, 12, true);
    HALF(hb + 3, 3, 12, true);
    if ((hb & 31) == 28) epilogue(hb >> 5);
  }
  HALF(508, 0, 12, true);    // stages half 511
  HALF(509, 1, 12, false);
  HALF(510, 2, 6,  false);
  HALF(511, 3, 0,  false);
  epilogue(15);
#undef HALF
#undef STAGE
}

// ---------- launch ----------
extern "C" void kernel_launch(void* const* d_in, const int* in_sizes, int n_in,
                              void* d_out, int out_size, void* d_ws, size_t ws_size,
                              hipStream_t stream) {
  const float* x     = (const float*)d_in[0];
  const float* h0    = (const float*)d_in[1];
  const float* Wd    = (const float*)d_in[2];
  const float* bd    = (const float*)d_in[3];
  const float* Wb    = (const float*)d_in[4];
  const float* bb    = (const float*)d_in[5];
  const float* A_log = (const float*)d_in[6];
  float* out = (float*)d_out;

  char* ws = (char*)d_ws;
  unsigned short* xb  = (unsigned short*)(ws + 0);           // 64 MiB
  unsigned short* wdb = (unsigned short*)(ws + 67108864);    //  2 MiB
  unsigned short* wbb = (unsigned short*)(ws + 69206016);    //  2 MiB

  // converts
  k_cvt<<<(M_DIM * K_DIM / 8) / 256, 256, 0, stream>>>(x, xb, M_DIM * K_DIM / 8);
  k_cvt<<<(H_DIM * K_DIM / 8) / 256, 256, 0, stream>>>(Wd, wdb, H_DIM * K_DIM / 8);
  k_cvt<<<(H_DIM * K_DIM / 8) / 256, 256, 0, stream>>>(Wb, wbb, H_DIM * K_DIM / 8);

  // fused dual GEMM + chunked scan + tanh; 512 blocks (2/CU), 256 thr
  k_mega<<<512, 256, 0, stream>>>(xb, wdb, wbb, bd, bb, A_log, h0, out);
}